// Round 4
// baseline (329.197 us; speedup 1.0000x reference)
//
#include <hip/hip_runtime.h>
#include <math.h>

#define BB 64
#define PP 100
#define NN 1000
#define DD 128
#define HH 8
#define QDQ 16
#define NTOT 1196
#define QTR 299      // keys per quarter
#define QCH 64       // keys per LDS chunk
#define QROWS 16
#define LOG2E 1.44269504088896f

// ---------------- Kernel W: transpose Wq and MC (128x128 each) ----------------
__global__ __launch_bounds__(256) void k_wt(const float* __restrict__ Wq,
                                            const float* __restrict__ MC,
                                            float* __restrict__ WqT,
                                            float* __restrict__ MCT) {
  int r = blockIdx.x;            // output row (d)
  int t = threadIdx.x;
  int j = t & 127;
  if (t < 128) WqT[r * DD + j] = Wq[j * DD + r];
  else         MCT[r * DD + j] = MC[j * DD + r];
}

// ---------------- Kernel A: q = q_first + x @ Wq^T (LDS-staged W^T GEMM) ------
__global__ __launch_bounds__(256) void k_qcalc(const float* __restrict__ x,
                                               const float* __restrict__ WqT,
                                               const float* __restrict__ qf,
                                               float* __restrict__ qout) {
  __shared__ float sw[64 * DD];        // 32 KB: one d-half of W^T
  __shared__ float xs[QROWS * DD];     // 8 KB
  int tid = threadIdx.x;
  int row0 = blockIdx.x * QROWS;

  for (int i = tid; i < QROWS * DD / 4; i += 256)
    ((float4*)xs)[i] = ((const float4*)(x + (size_t)row0 * DD))[i];

  int j = tid & 127, rr = tid >> 7;
  float acc[8];
#pragma unroll
  for (int i = 0; i < 8; ++i) acc[i] = 0.f;

  for (int half = 0; half < 2; ++half) {
    __syncthreads();
    for (int i = tid; i < 64 * DD / 4; i += 256)
      ((float4*)sw)[i] = ((const float4*)(WqT + half * 64 * DD))[i];
    __syncthreads();
#pragma unroll
    for (int ri = 0; ri < 8; ++ri) {
      int r = 2 * ri + rr;
      float a = acc[ri];
#pragma unroll 16
      for (int d = 0; d < 64; ++d)
        a += xs[r * DD + half * 64 + d] * sw[d * DD + j];
      acc[ri] = a;
    }
  }
#pragma unroll
  for (int ri = 0; ri < 8; ++ri) {
    int bp = row0 + 2 * ri + rr;
    int b = bp / PP, p = bp % PP;
    int h = j >> 4, qd = j & 15;
    size_t qi = ((size_t)(b * HH + h) * PP + p) * QDQ + qd;
    qout[qi] = acc[ri] + qf[qi];
  }
}

// ---------------- Kernel F: mask transpose+pad, scaled by log2e ---------------
__global__ __launch_bounds__(256) void k_mask_t(const float* __restrict__ mask,
                                                float* __restrict__ mt) {
  __shared__ float tile[64][65];
  int nt = blockIdx.x;           // 19 tiles over n (0..1215, pad to NTOT)
  int pt = blockIdx.y;           // 2 tiles over p (0..127)
  int b  = blockIdx.z;
  int tx = threadIdx.x & 63, ty = threadIdx.x >> 6;
  int n0 = nt * 64, p0 = pt * 64;
#pragma unroll
  for (int r = ty; r < 64; r += 4) {
    int p = p0 + r, n = n0 + tx;
    tile[r][tx] = (p < PP && n < NN) ? mask[((size_t)b * PP + p) * NN + n] * LOG2E : 0.f;
  }
  __syncthreads();
#pragma unroll
  for (int r = ty; r < 64; r += 4) {
    int n = n0 + r, p = p0 + tx;
    if (n < NTOT) mt[((size_t)b * NTOT + n) * 128 + p] = tile[tx][r];
  }
}

// ---------------- Kernel B: MHA partial (exp2 domain), 256-thr blocks ---------
// grid = 2048 (XCD-swizzled: 512 bh * 4 key-quarters); block = 256 (2 groups)
__global__ __launch_bounds__(256, 8) void k_mha(const float* __restrict__ kk,
                                                const float* __restrict__ vv,
                                                const float* __restrict__ qws,
                                                const float* __restrict__ mt,
                                                float* __restrict__ part) {
  int bid = blockIdx.x;
  int swz = (bid & 7) * 256 + (bid >> 3);      // 32 blocks of same b per XCD
  int bh = swz >> 2, quarter = swz & 3;
  int b = bh >> 3;
  int tid = threadIdx.x;
  int g = tid >> 7;           // key-group 0..1
  int p = tid & 127;          // lane-query
  int pc = p < PP ? p : PP - 1;

  __shared__ __align__(16) float4 s4[1024];    // 16 KB: [buf(2)][k 256 | v 256]

  float q[QDQ];
  const float* qrow = qws + ((size_t)bh * PP + pc) * QDQ;
#pragma unroll
  for (int jj = 0; jj < QDQ; jj += 4) {
    float4 q4 = *(const float4*)(qrow + jj);
    const float sc0 = 0.25f * LOG2E;           // fold 1/sqrt(16) and log2(e)
    q[jj] = q4.x * sc0; q[jj + 1] = q4.y * sc0;
    q[jj + 2] = q4.z * sc0; q[jj + 3] = q4.w * sc0;
  }

  float acc[QDQ];
#pragma unroll
  for (int jj = 0; jj < QDQ; ++jj) acc[jj] = 0.f;
  float m = -1e30f, l = 0.f;                   // m in log2 domain

  const float4* kg4 = (const float4*)(kk + (size_t)bh * NTOT * QDQ);
  const float4* vg4 = (const float4*)(vv + (size_t)bh * NTOT * QDQ);
  int key0 = quarter * QTR;
  int gbase = key0 * 4;
  int lim = NTOT * 4 - 1;

  float4 rk, rv;
  { int gi = gbase + tid; gi = gi < lim ? gi : lim; rk = kg4[gi]; rv = vg4[gi]; }

  int cur = 0;
  for (int c = 0; c < 5; ++c) {                // 299 = 4*64 + 43
    int base = c * QCH;
    int L = QTR - base; if (L > QCH) L = QCH;
    __syncthreads();                           // buf[cur] free
    s4[cur * 512 + tid] = rk;
    s4[cur * 512 + 256 + tid] = rv;
    __syncthreads();
    if (c < 4) {                               // prefetch next chunk into regs
      int gi = gbase + (c + 1) * 256 + tid; gi = gi < lim ? gi : lim;
      rk = kg4[gi]; rv = vg4[gi];
    }
    const float* mrow = mt + ((size_t)b * NTOT + key0 + base) * 128 + pc;
    int kb = cur * 512, vb = cur * 512 + 256;
#pragma unroll 2
    for (int i = g; i < L; i += 2) {
      float mk = mrow[i * 128];
      float4 k0 = s4[kb + i * 4 + 0], k1 = s4[kb + i * 4 + 1];
      float4 k2 = s4[kb + i * 4 + 2], k3 = s4[kb + i * 4 + 3];
      float sA = q[0] * k0.x + q[1] * k0.y + q[2] * k0.z + q[3] * k0.w;
      float sB = q[4] * k1.x + q[5] * k1.y + q[6] * k1.z + q[7] * k1.w;
      float sC = q[8] * k2.x + q[9] * k2.y + q[10] * k2.z + q[11] * k2.w;
      float sD = q[12] * k3.x + q[13] * k3.y + q[14] * k3.z + q[15] * k3.w;
      float s = (sA + sB) + (sC + sD) + mk;    // log2-domain score

      if (s > m + 8.f) {                       // deferred-max rescale (rare)
        float cc = exp2f(m - s);
        l *= cc;
#pragma unroll
        for (int jj = 0; jj < QDQ; ++jj) acc[jj] *= cc;
        m = s;
      }
      float w = exp2f(s - m);                  // bare v_exp_f32
      l += w;
      float4 v0 = s4[vb + i * 4 + 0], v1 = s4[vb + i * 4 + 1];
      float4 v2 = s4[vb + i * 4 + 2], v3 = s4[vb + i * 4 + 3];
      acc[0] += w * v0.x;  acc[1] += w * v0.y;  acc[2] += w * v0.z;  acc[3] += w * v0.w;
      acc[4] += w * v1.x;  acc[5] += w * v1.y;  acc[6] += w * v1.z;  acc[7] += w * v1.w;
      acc[8] += w * v2.x;  acc[9] += w * v2.y;  acc[10] += w * v2.z; acc[11] += w * v2.w;
      acc[12] += w * v3.x; acc[13] += w * v3.y; acc[14] += w * v3.z; acc[15] += w * v3.w;
    }
    cur ^= 1;
  }

  __syncthreads();                             // reuse smem for 2-way merge
  float* sm = (float*)s4;
  if (p < PP) {
    float* pl = sm + ((size_t)(g * PP + p)) * 18;
#pragma unroll
    for (int jj = 0; jj < QDQ; ++jj) pl[jj] = acc[jj];
    pl[16] = m;
    pl[17] = l;
  }
  __syncthreads();
  for (int idx = tid; idx < PP * QDQ; idx += 256) {
    int pp2 = idx >> 4, qd = idx & 15;
    float m0 = sm[(0 * PP + pp2) * 18 + 16], l0 = sm[(0 * PP + pp2) * 18 + 17];
    float m1 = sm[(1 * PP + pp2) * 18 + 16], l1 = sm[(1 * PP + pp2) * 18 + 17];
    float M = fmaxf(m0, m1);
    float c0 = exp2f(m0 - M), c1 = exp2f(m1 - M);
    float A = sm[(0 * PP + pp2) * 18 + qd] * c0 + sm[(1 * PP + pp2) * 18 + qd] * c1;
    float* o = part + ((size_t)swz * PP + pp2) * 18;
    o[qd] = A;
    if (qd == 0) {
      o[16] = M;                               // log2 domain
      o[17] = l0 * c0 + l1 * c1;
    }
  }
}

// ---------------- Kernel C: merge 4 quarters + mh_combine (LDS W^T GEMM) ------
__global__ __launch_bounds__(256) void k_combine(const float* __restrict__ part,
                                                 const float* __restrict__ MCT,
                                                 float* __restrict__ mh) {
  __shared__ float sw[64 * DD];        // 32 KB
  __shared__ float oc[QROWS * DD];     // 8 KB
  int tid = threadIdx.x;
  int row0 = blockIdx.x * QROWS;

  for (int i = tid; i < QROWS * DD; i += 256) {
    int r = i >> 7, t = i & 127;
    int bp = row0 + r, b = bp / PP, p = bp % PP;
    int qd = t & 15, h = t >> 4;
    int bh = b * HH + h;
    const float* r0 = part + ((size_t)(bh * 4 + 0) * PP + p) * 18;
    const float* r1 = part + ((size_t)(bh * 4 + 1) * PP + p) * 18;
    const float* r2 = part + ((size_t)(bh * 4 + 2) * PP + p) * 18;
    const float* r3 = part + ((size_t)(bh * 4 + 3) * PP + p) * 18;
    float m0 = r0[16], m1 = r1[16], m2 = r2[16], m3 = r3[16];
    float M = fmaxf(fmaxf(m0, m1), fmaxf(m2, m3));
    float c0 = exp2f(m0 - M), c1 = exp2f(m1 - M);
    float c2 = exp2f(m2 - M), c3 = exp2f(m3 - M);
    float L = r0[17] * c0 + r1[17] * c1 + r2[17] * c2 + r3[17] * c3;
    oc[i] = (r0[qd] * c0 + r1[qd] * c1 + r2[qd] * c2 + r3[qd] * c3) / L;
  }

  int j = tid & 127, rr = tid >> 7;
  float acc[8];
#pragma unroll
  for (int i = 0; i < 8; ++i) acc[i] = 0.f;

  for (int half = 0; half < 2; ++half) {
    __syncthreads();
    for (int i = tid; i < 64 * DD / 4; i += 256)
      ((float4*)sw)[i] = ((const float4*)(MCT + half * 64 * DD))[i];
    __syncthreads();
#pragma unroll
    for (int ri = 0; ri < 8; ++ri) {
      int r = 2 * ri + rr;
      float a = acc[ri];
#pragma unroll 16
      for (int d = 0; d < 64; ++d)
        a += oc[r * DD + half * 64 + d] * sw[d * DD + j];
      acc[ri] = a;
    }
  }
#pragma unroll
  for (int ri = 0; ri < 8; ++ri) {
    int bp = row0 + 2 * ri + rr;
    mh[(size_t)bp * DD + j] = acc[ri];
  }
}

// ---------------- Kernel D: score2[b,p,n] = sum_d mh[b,p,d]*shk[b,d,n] --------
__global__ __launch_bounds__(256) void k_score2(const float* __restrict__ mh,
                                                const float* __restrict__ shk,
                                                float* __restrict__ sc) {
  int bid = blockIdx.x;
  int swz = (bid & 7) * 128 + (bid >> 3);      // same-b blocks share an XCD
  int b = swz >> 4, nt = swz & 15;
  int tid = threadIdx.x; int nl = tid & 31, pg = tid >> 5;
  __shared__ float A[PP * 132];
  for (int idx = tid; idx < PP * DD; idx += 256)
    A[(idx >> 7) * 132 + (idx & 127)] = mh[(size_t)b * PP * DD + idx];
  __syncthreads();

  int na = nt * 64 + nl, nb2 = na + 32;
  int nca = na < NN ? na : NN - 1, ncb = nb2 < NN ? nb2 : NN - 1;
  const float* S = shk + (size_t)b * DD * NN;
  float acc0[13], acc1[13];
#pragma unroll
  for (int i = 0; i < 13; ++i) { acc0[i] = 0.f; acc1[i] = 0.f; }

  for (int d = 0; d < DD; d += 4) {
    float sa0 = S[(size_t)(d + 0) * NN + nca];
    float sa1 = S[(size_t)(d + 1) * NN + nca];
    float sa2 = S[(size_t)(d + 2) * NN + nca];
    float sa3 = S[(size_t)(d + 3) * NN + nca];
    float sb0 = S[(size_t)(d + 0) * NN + ncb];
    float sb1 = S[(size_t)(d + 1) * NN + ncb];
    float sb2 = S[(size_t)(d + 2) * NN + ncb];
    float sb3 = S[(size_t)(d + 3) * NN + ncb];
#pragma unroll
    for (int i = 0; i < 13; ++i) {
      int p = pg + (i << 3);
      if (p < PP) {
        const float4 a4 = *(const float4*)&A[p * 132 + d];
        acc0[i] += a4.x * sa0 + a4.y * sa1 + a4.z * sa2 + a4.w * sa3;
        acc1[i] += a4.x * sb0 + a4.y * sb1 + a4.z * sb2 + a4.w * sb3;
      }
    }
  }
#pragma unroll
  for (int i = 0; i < 13; ++i) {
    int p = pg + (i << 3);
    if (p < PP) {
      size_t base = ((size_t)b * PP + p) * NN;
      if (na < NN) sc[base + na] = acc0[i];
      if (nb2 < NN) sc[base + nb2] = acc1[i];
    }
  }
}

// ---------------- Kernel E: fast-tanh clip + edge bias + mask + row softmax ---
__global__ __launch_bounds__(256) void k_finsm(const float* __restrict__ sc,
                                               const float* __restrict__ eb,
                                               const int* __restrict__ cn,
                                               const float* __restrict__ mask,
                                               float* __restrict__ out) {
  int bid = blockIdx.x;
  int bp = (bid & 7) * 800 + (bid >> 3);       // XCD swizzle (6400 % 8 == 0)
  int b = bp / PP;
  int t = threadIdx.x;
  int node = cn[bp];
  const float* scp = sc + (size_t)bp * NN;
  const float* ebp = eb + ((size_t)b * NN + node) * NN;
  const float* mp = mask + (size_t)bp * NN;
  const float inv_sqrtD = 0.08838834764831845f;  // 1/sqrt(128)

  float vals[4];
  float m = -1e30f;
#pragma unroll
  for (int i = 0; i < 4; ++i) {
    int n = t + (i << 8);
    if (n < NN) {
      float z = scp[n] * inv_sqrtD;
      float e = __expf(2.f * z);
      float th10 = 10.f - 20.f * __builtin_amdgcn_rcpf(e + 1.f);  // 10*tanh(z)
      float lg = th10 + ebp[n] + mp[n];
      vals[i] = lg;
      m = fmaxf(m, lg);
    } else {
      vals[i] = -1e30f;
    }
  }
#pragma unroll
  for (int off = 32; off; off >>= 1) m = fmaxf(m, __shfl_xor(m, off));
  __shared__ float red[4];
  int w = t >> 6, lane = t & 63;
  if (lane == 0) red[w] = m;
  __syncthreads();
  m = fmaxf(fmaxf(red[0], red[1]), fmaxf(red[2], red[3]));
  __syncthreads();

  float s = 0.f;
#pragma unroll
  for (int i = 0; i < 4; ++i) {
    int n = t + (i << 8);
    float e = (n < NN) ? __expf(vals[i] - m) : 0.f;
    vals[i] = e;
    s += e;
  }
#pragma unroll
  for (int off = 32; off; off >>= 1) s += __shfl_xor(s, off);
  if (lane == 0) red[w] = s;
  __syncthreads();
  s = red[0] + red[1] + red[2] + red[3];
  float inv = 1.f / s;
#pragma unroll
  for (int i = 0; i < 4; ++i) {
    int n = t + (i << 8);
    if (n < NN) out[(size_t)bp * NN + n] = vals[i] * inv;
  }
}

extern "C" void kernel_launch(void* const* d_in, const int* in_sizes, int n_in,
                              void* d_out, int out_size, void* d_ws, size_t ws_size,
                              hipStream_t stream) {
  const float* x    = (const float*)d_in[0];   // encoded_last_node (B,P,D)
  const float* mask = (const float*)d_in[1];   // ninf_mask (B,P,N)
  const float* qf   = (const float*)d_in[2];   // q_first (B,H,P,QD)
  const float* kk   = (const float*)d_in[3];   // k (B,H,NTOT,QD)
  const float* vv   = (const float*)d_in[4];   // v (B,H,NTOT,QD)
  const float* shk  = (const float*)d_in[5];   // single_head_key (B,D,N)
  const float* Wq   = (const float*)d_in[6];   // (128,128)
  const float* MC   = (const float*)d_in[7];   // (128,128)
  const float* eb   = (const float*)d_in[8];   // edge_bias (B,N,N)
  const int*   cn   = (const int*)d_in[9];     // current_node (B,P)

  float* out = (float*)d_out;
  float* ws = (float*)d_ws;
  float* q_ws = ws;                                   //   819,200 f
  float* part = ws + 819200;                          // 3,686,400 f (2048*100*18)
  float* mh   = ws + 4505600;                         //   819,200 f
  float* mt   = ws + 5324800;                         // 9,797,632 f (B*NTOT*128)
  float* sc   = mt;  // score2 overlays mt (written only after last mt read)
  float* wqt  = ws + 15122432;                        //    16,384 f
  float* mct  = ws + 15138816;                        //    16,384 f

  hipLaunchKernelGGL(k_wt, dim3(128), dim3(256), 0, stream, Wq, MC, wqt, mct);
  hipLaunchKernelGGL(k_qcalc, dim3(400), dim3(256), 0, stream, x, wqt, qf, q_ws);
  hipLaunchKernelGGL(k_mask_t, dim3(19, 2, BB), dim3(256), 0, stream, mask, mt);
  hipLaunchKernelGGL(k_mha, dim3(2048), dim3(256), 0, stream, kk, vv, q_ws, mt, part);
  hipLaunchKernelGGL(k_combine, dim3(400), dim3(256), 0, stream, part, mct, mh);
  hipLaunchKernelGGL(k_score2, dim3(1024), dim3(256), 0, stream, mh, shk, sc);
  hipLaunchKernelGGL(k_finsm, dim3(6400), dim3(256), 0, stream, sc, eb, cn, mask, out);
}

// Round 6
// 246.385 us; speedup vs baseline: 1.3361x; 1.3361x over previous
//
#include <hip/hip_runtime.h>
#include <math.h>

#define BB 64
#define PP 100
#define NN 1000
#define DD 128
#define HH 8
#define QDQ 16
#define NTOT 1196
#define HALFK 598
#define CH 128
#define QROWS 16
#define LOG2E 1.44269504088896f

// ---------------- Kernel W: transpose Wq and MC (128x128 each) ----------------
__global__ __launch_bounds__(256) void k_wt(const float* __restrict__ Wq,
                                            const float* __restrict__ MC,
                                            float* __restrict__ WqT,
                                            float* __restrict__ MCT) {
  int r = blockIdx.x;            // output row (d)
  int t = threadIdx.x;
  int j = t & 127;
  if (t < 128) WqT[r * DD + j] = Wq[j * DD + r];
  else         MCT[r * DD + j] = MC[j * DD + r];
}

// ---------------- Kernel A: q = q_first + x @ Wq^T (LDS-staged W^T GEMM) ------
__global__ __launch_bounds__(256) void k_qcalc(const float* __restrict__ x,
                                               const float* __restrict__ WqT,
                                               const float* __restrict__ qf,
                                               float* __restrict__ qout) {
  __shared__ float sw[64 * DD];        // 32 KB: one d-half of W^T
  __shared__ float xs[QROWS * DD];     // 8 KB
  int tid = threadIdx.x;
  int row0 = blockIdx.x * QROWS;

  for (int i = tid; i < QROWS * DD / 4; i += 256)
    ((float4*)xs)[i] = ((const float4*)(x + (size_t)row0 * DD))[i];

  int j = tid & 127, rr = tid >> 7;
  float acc[8];
#pragma unroll
  for (int i = 0; i < 8; ++i) acc[i] = 0.f;

  for (int half = 0; half < 2; ++half) {
    __syncthreads();
    for (int i = tid; i < 64 * DD / 4; i += 256)
      ((float4*)sw)[i] = ((const float4*)(WqT + half * 64 * DD))[i];
    __syncthreads();
#pragma unroll
    for (int ri = 0; ri < 8; ++ri) {
      int r = 2 * ri + rr;
      float a = acc[ri];
#pragma unroll 16
      for (int d = 0; d < 64; ++d)
        a += xs[r * DD + half * 64 + d] * sw[d * DD + j];
      acc[ri] = a;
    }
  }
#pragma unroll
  for (int ri = 0; ri < 8; ++ri) {
    int bp = row0 + 2 * ri + rr;
    int b = bp / PP, p = bp % PP;
    int h = j >> 4, qd = j & 15;
    size_t qi = ((size_t)(b * HH + h) * PP + p) * QDQ + qd;
    qout[qi] = acc[ri] + qf[qi];
  }
}

// ---------------- Kernel F: mask transpose+pad, scaled by log2e ---------------
__global__ __launch_bounds__(256) void k_mask_t(const float* __restrict__ mask,
                                                float* __restrict__ mt) {
  __shared__ float tile[64][65];
  int nt = blockIdx.x;           // 19 tiles over n (0..1215, pad to NTOT)
  int pt = blockIdx.y;           // 2 tiles over p (0..127)
  int b  = blockIdx.z;
  int tx = threadIdx.x & 63, ty = threadIdx.x >> 6;
  int n0 = nt * 64, p0 = pt * 64;
#pragma unroll
  for (int r = ty; r < 64; r += 4) {
    int p = p0 + r, n = n0 + tx;
    tile[r][tx] = (p < PP && n < NN) ? mask[((size_t)b * PP + p) * NN + n] * LOG2E : 0.f;
  }
  __syncthreads();
#pragma unroll
  for (int r = ty; r < 64; r += 4) {
    int n = n0 + r, p = p0 + tx;
    if (n < NTOT) mt[((size_t)b * NTOT + n) * 128 + p] = tile[tx][r];
  }
}

// ---------------- Kernel B: MHA partial (exp2 domain), 4-key batched ----------
// grid = 1024 (XCD-swizzled: 512 bh * 2 halves); block = 512 (4 key-groups)
#define KDOT(ii, sv) { \
  float4 K0 = s4[kb + (ii) * 4 + 0], K1 = s4[kb + (ii) * 4 + 1]; \
  float4 K2 = s4[kb + (ii) * 4 + 2], K3 = s4[kb + (ii) * 4 + 3]; \
  sv = q[0] * K0.x + q[1] * K0.y + q[2] * K0.z + q[3] * K0.w \
     + q[4] * K1.x + q[5] * K1.y + q[6] * K1.z + q[7] * K1.w \
     + q[8] * K2.x + q[9] * K2.y + q[10] * K2.z + q[11] * K2.w \
     + q[12] * K3.x + q[13] * K3.y + q[14] * K3.z + q[15] * K3.w; }

#define PVACC(ii, wt) { \
  float4 V0 = s4[vb + (ii) * 4 + 0], V1 = s4[vb + (ii) * 4 + 1]; \
  float4 V2 = s4[vb + (ii) * 4 + 2], V3 = s4[vb + (ii) * 4 + 3]; \
  acc[0] += (wt) * V0.x;  acc[1] += (wt) * V0.y;  acc[2] += (wt) * V0.z;  acc[3] += (wt) * V0.w; \
  acc[4] += (wt) * V1.x;  acc[5] += (wt) * V1.y;  acc[6] += (wt) * V1.z;  acc[7] += (wt) * V1.w; \
  acc[8] += (wt) * V2.x;  acc[9] += (wt) * V2.y;  acc[10] += (wt) * V2.z; acc[11] += (wt) * V2.w; \
  acc[12] += (wt) * V3.x; acc[13] += (wt) * V3.y; acc[14] += (wt) * V3.z; acc[15] += (wt) * V3.w; }

__global__ __launch_bounds__(512) void k_mha(const float* __restrict__ kk,
                                             const float* __restrict__ vv,
                                             const float* __restrict__ qws,
                                             const float* __restrict__ mt,
                                             float* __restrict__ part) {
  int bid = blockIdx.x;
  int swz = (bid & 7) * 128 + (bid >> 3);      // 16 blocks of same b per XCD
  int bh = swz >> 1, half = swz & 1;
  int b = bh >> 3;
  int tid = threadIdx.x;
  int g = tid >> 7;           // key-group 0..3
  int p = tid & 127;          // lane-query
  int pc = p < PP ? p : PP - 1;

  __shared__ __align__(16) float4 s4[2048];    // 32 KB: [buf(2)][k 512 | v 512]

  float q[QDQ];
  const float* qrow = qws + ((size_t)bh * PP + pc) * QDQ;
#pragma unroll
  for (int jj = 0; jj < QDQ; jj += 4) {
    float4 q4 = *(const float4*)(qrow + jj);
    const float sc0 = 0.25f * LOG2E;           // fold 1/sqrt(16) and log2(e)
    q[jj] = q4.x * sc0; q[jj + 1] = q4.y * sc0;
    q[jj + 2] = q4.z * sc0; q[jj + 3] = q4.w * sc0;
  }

  float acc[QDQ];
#pragma unroll
  for (int jj = 0; jj < QDQ; ++jj) acc[jj] = 0.f;
  float m = -1e30f, l = 0.f;                   // m in log2 domain

  const float4* kg4 = (const float4*)(kk + (size_t)bh * NTOT * QDQ);
  const float4* vg4 = (const float4*)(vv + (size_t)bh * NTOT * QDQ);
  int key0 = half * HALFK;
  int gbase = key0 * 4;
  int lim = NTOT * 4 - 1;

  float4 rk, rv;
  { int gi = gbase + tid; gi = gi < lim ? gi : lim; rk = kg4[gi]; rv = vg4[gi]; }

  int cur = 0;
  for (int c = 0; c < 5; ++c) {                // 598 = 4*128 + 86
    int base = c * CH;
    int L = HALFK - base; if (L > CH) L = CH;
    __syncthreads();                           // buf[cur] free
    s4[cur * 1024 + tid] = rk;
    s4[cur * 1024 + 512 + tid] = rv;
    __syncthreads();
    if (c < 4) {                               // prefetch next chunk into regs
      int gi = gbase + (c + 1) * 512 + tid; gi = gi < lim ? gi : lim;
      rk = kg4[gi]; rv = vg4[gi];
    }
    const float* mrow = mt + ((size_t)b * NTOT + key0 + base) * 128 + pc;
    int kb = cur * 1024, vb = cur * 1024 + 512;

    int i = g;
    for (; i + 12 < L; i += 16) {              // 4-key batch per group
      float mk0 = mrow[(i + 0) * 128];
      float mk1 = mrow[(i + 4) * 128];
      float mk2 = mrow[(i + 8) * 128];
      float mk3 = mrow[(i + 12) * 128];
      float s0, s1, s2, s3;
      KDOT(i + 0, s0)
      KDOT(i + 4, s1)
      KDOT(i + 8, s2)
      KDOT(i + 12, s3)
      s0 += mk0; s1 += mk1; s2 += mk2; s3 += mk3;
      float mx = fmaxf(fmaxf(s0, s1), fmaxf(s2, s3));
      if (mx > m + 8.f) {                      // deferred-max rescale (rare)
        float cc = exp2f(m - mx);
        l *= cc;
#pragma unroll
        for (int jj = 0; jj < QDQ; ++jj) acc[jj] *= cc;
        m = mx;
      }
      float w0 = exp2f(s0 - m), w1 = exp2f(s1 - m);
      float w2 = exp2f(s2 - m), w3 = exp2f(s3 - m);
      l += (w0 + w1) + (w2 + w3);
      PVACC(i + 0, w0)
      PVACC(i + 4, w1)
      PVACC(i + 8, w2)
      PVACC(i + 12, w3)
    }
    for (; i < L; i += 4) {                    // tail keys
      float mk = mrow[i * 128];
      float s0;
      KDOT(i, s0)
      s0 += mk;
      if (s0 > m + 8.f) {
        float cc = exp2f(m - s0);
        l *= cc;
#pragma unroll
        for (int jj = 0; jj < QDQ; ++jj) acc[jj] *= cc;
        m = s0;
      }
      float wv = exp2f(s0 - m);
      l += wv;
      PVACC(i, wv)
    }
    cur ^= 1;
  }

  __syncthreads();                             // reuse smem for 4-way merge
  float* sm = (float*)s4;
  if (p < PP) {
    float* pl = sm + ((size_t)(g * PP + p)) * 18;
#pragma unroll
    for (int jj = 0; jj < QDQ; ++jj) pl[jj] = acc[jj];
    pl[16] = m;
    pl[17] = l;
  }
  __syncthreads();
  for (int idx = tid; idx < PP * QDQ; idx += 512) {
    int pp2 = idx >> 4, qd = idx & 15;
    float m0 = sm[(0 * PP + pp2) * 18 + 16], l0 = sm[(0 * PP + pp2) * 18 + 17];
    float m1 = sm[(1 * PP + pp2) * 18 + 16], l1 = sm[(1 * PP + pp2) * 18 + 17];
    float m2 = sm[(2 * PP + pp2) * 18 + 16], l2 = sm[(2 * PP + pp2) * 18 + 17];
    float m3 = sm[(3 * PP + pp2) * 18 + 16], l3 = sm[(3 * PP + pp2) * 18 + 17];
    float M = fmaxf(fmaxf(m0, m1), fmaxf(m2, m3));
    float c0 = exp2f(m0 - M), c1 = exp2f(m1 - M);
    float c2 = exp2f(m2 - M), c3 = exp2f(m3 - M);
    float A = sm[(0 * PP + pp2) * 18 + qd] * c0 + sm[(1 * PP + pp2) * 18 + qd] * c1
            + sm[(2 * PP + pp2) * 18 + qd] * c2 + sm[(3 * PP + pp2) * 18 + qd] * c3;
    float* o = part + ((size_t)swz * PP + pp2) * 18;
    o[qd] = A;
    if (qd == 0) {
      o[16] = M;                               // log2 domain
      o[17] = l0 * c0 + l1 * c1 + l2 * c2 + l3 * c3;
    }
  }
}

// ---------------- Kernel C: merge 2 halves + mh_combine (LDS W^T GEMM) --------
__global__ __launch_bounds__(256) void k_combine(const float* __restrict__ part,
                                                 const float* __restrict__ MCT,
                                                 float* __restrict__ mh) {
  __shared__ float sw[64 * DD];        // 32 KB
  __shared__ float oc[QROWS * DD];     // 8 KB
  int tid = threadIdx.x;
  int row0 = blockIdx.x * QROWS;

  for (int i = tid; i < QROWS * DD; i += 256) {
    int r = i >> 7, t = i & 127;
    int bp = row0 + r, b = bp / PP, p = bp % PP;
    int qd = t & 15, h = t >> 4;
    int bh = b * HH + h;
    const float* r0 = part + ((size_t)(bh * 2 + 0) * PP + p) * 18;
    const float* r1 = part + ((size_t)(bh * 2 + 1) * PP + p) * 18;
    float m0 = r0[16], l0 = r0[17], m1 = r1[16], l1 = r1[17];
    float M = fmaxf(m0, m1);
    float c0 = exp2f(m0 - M), c1 = exp2f(m1 - M);
    float L = l0 * c0 + l1 * c1;
    oc[i] = (r0[qd] * c0 + r1[qd] * c1) / L;
  }

  int j = tid & 127, rr = tid >> 7;
  float acc[8];
#pragma unroll
  for (int i = 0; i < 8; ++i) acc[i] = 0.f;

  for (int half = 0; half < 2; ++half) {
    __syncthreads();
    for (int i = tid; i < 64 * DD / 4; i += 256)
      ((float4*)sw)[i] = ((const float4*)(MCT + half * 64 * DD))[i];
    __syncthreads();
#pragma unroll
    for (int ri = 0; ri < 8; ++ri) {
      int r = 2 * ri + rr;
      float a = acc[ri];
#pragma unroll 16
      for (int d = 0; d < 64; ++d)
        a += oc[r * DD + half * 64 + d] * sw[d * DD + j];
      acc[ri] = a;
    }
  }
#pragma unroll
  for (int ri = 0; ri < 8; ++ri) {
    int bp = row0 + 2 * ri + rr;
    mh[(size_t)bp * DD + j] = acc[ri];
  }
}

// ---------------- Kernel D: score2[b,p,n] = sum_d mh[b,p,d]*shk[b,d,n] --------
__global__ __launch_bounds__(256) void k_score2(const float* __restrict__ mh,
                                                const float* __restrict__ shk,
                                                float* __restrict__ sc) {
  int bid = blockIdx.x;
  int swz = (bid & 7) * 128 + (bid >> 3);      // same-b blocks share an XCD
  int b = swz >> 4, nt = swz & 15;
  int tid = threadIdx.x; int nl = tid & 31, pg = tid >> 5;
  __shared__ float A[PP * 132];
  for (int idx = tid; idx < PP * DD; idx += 256)
    A[(idx >> 7) * 132 + (idx & 127)] = mh[(size_t)b * PP * DD + idx];
  __syncthreads();

  int na = nt * 64 + nl, nb2 = na + 32;
  int nca = na < NN ? na : NN - 1, ncb = nb2 < NN ? nb2 : NN - 1;
  const float* S = shk + (size_t)b * DD * NN;
  float acc0[13], acc1[13];
#pragma unroll
  for (int i = 0; i < 13; ++i) { acc0[i] = 0.f; acc1[i] = 0.f; }

  for (int d = 0; d < DD; d += 4) {
    float sa0 = S[(size_t)(d + 0) * NN + nca];
    float sa1 = S[(size_t)(d + 1) * NN + nca];
    float sa2 = S[(size_t)(d + 2) * NN + nca];
    float sa3 = S[(size_t)(d + 3) * NN + nca];
    float sb0 = S[(size_t)(d + 0) * NN + ncb];
    float sb1 = S[(size_t)(d + 1) * NN + ncb];
    float sb2 = S[(size_t)(d + 2) * NN + ncb];
    float sb3 = S[(size_t)(d + 3) * NN + ncb];
#pragma unroll
    for (int i = 0; i < 13; ++i) {
      int p = pg + (i << 3);
      if (p < PP) {
        const float4 a4 = *(const float4*)&A[p * 132 + d];
        acc0[i] += a4.x * sa0 + a4.y * sa1 + a4.z * sa2 + a4.w * sa3;
        acc1[i] += a4.x * sb0 + a4.y * sb1 + a4.z * sb2 + a4.w * sb3;
      }
    }
  }
#pragma unroll
  for (int i = 0; i < 13; ++i) {
    int p = pg + (i << 3);
    if (p < PP) {
      size_t base = ((size_t)b * PP + p) * NN;
      if (na < NN) sc[base + na] = acc0[i];
      if (nb2 < NN) sc[base + nb2] = acc1[i];
    }
  }
}

// ---------------- Kernel E: fast-tanh clip + edge bias + mask + row softmax ---
__global__ __launch_bounds__(256) void k_finsm(const float* __restrict__ sc,
                                               const float* __restrict__ eb,
                                               const int* __restrict__ cn,
                                               const float* __restrict__ mask,
                                               float* __restrict__ out) {
  int bid = blockIdx.x;
  int bp = (bid & 7) * 800 + (bid >> 3);       // XCD swizzle (6400 % 8 == 0)
  int b = bp / PP;
  int t = threadIdx.x;
  int node = cn[bp];
  const float* scp = sc + (size_t)bp * NN;
  const float* ebp = eb + ((size_t)b * NN + node) * NN;
  const float* mp = mask + (size_t)bp * NN;
  const float inv_sqrtD = 0.08838834764831845f;  // 1/sqrt(128)

  float vals[4];
  float m = -1e30f;
#pragma unroll
  for (int i = 0; i < 4; ++i) {
    int n = t + (i << 8);
    if (n < NN) {
      float z = scp[n] * inv_sqrtD;
      float e = __expf(2.f * z);
      float th10 = 10.f - 20.f * __builtin_amdgcn_rcpf(e + 1.f);  // 10*tanh(z)
      float lg = th10 + ebp[n] + mp[n];
      vals[i] = lg;
      m = fmaxf(m, lg);
    } else {
      vals[i] = -1e30f;
    }
  }
#pragma unroll
  for (int off = 32; off; off >>= 1) m = fmaxf(m, __shfl_xor(m, off));
  __shared__ float red[4];
  int w = t >> 6, lane = t & 63;
  if (lane == 0) red[w] = m;
  __syncthreads();
  m = fmaxf(fmaxf(red[0], red[1]), fmaxf(red[2], red[3]));
  __syncthreads();

  float s = 0.f;
#pragma unroll
  for (int i = 0; i < 4; ++i) {
    int n = t + (i << 8);
    float e = (n < NN) ? __expf(vals[i] - m) : 0.f;
    vals[i] = e;
    s += e;
  }
#pragma unroll
  for (int off = 32; off; off >>= 1) s += __shfl_xor(s, off);
  if (lane == 0) red[w] = s;
  __syncthreads();
  s = red[0] + red[1] + red[2] + red[3];
  float inv = 1.f / s;
#pragma unroll
  for (int i = 0; i < 4; ++i) {
    int n = t + (i << 8);
    if (n < NN) out[(size_t)bp * NN + n] = vals[i] * inv;
  }
}

extern "C" void kernel_launch(void* const* d_in, const int* in_sizes, int n_in,
                              void* d_out, int out_size, void* d_ws, size_t ws_size,
                              hipStream_t stream) {
  const float* x    = (const float*)d_in[0];   // encoded_last_node (B,P,D)
  const float* mask = (const float*)d_in[1];   // ninf_mask (B,P,N)
  const float* qf   = (const float*)d_in[2];   // q_first (B,H,P,QD)
  const float* kk   = (const float*)d_in[3];   // k (B,H,NTOT,QD)
  const float* vv   = (const float*)d_in[4];   // v (B,H,NTOT,QD)
  const float* shk  = (const float*)d_in[5];   // single_head_key (B,D,N)
  const float* Wq   = (const float*)d_in[6];   // (128,128)
  const float* MC   = (const float*)d_in[7];   // (128,128)
  const float* eb   = (const float*)d_in[8];   // edge_bias (B,N,N)
  const int*   cn   = (const int*)d_in[9];     // current_node (B,P)

  float* out = (float*)d_out;
  float* ws = (float*)d_ws;
  float* q_ws = ws;                                   //   819,200 f
  float* part = ws + 819200;                          // 1,843,200 f (1024*100*18)
  float* mh   = ws + 819200 + 1843200;                //   819,200 f
  float* mt   = ws + 819200 + 1843200 + 819200;       // 9,797,632 f (B*NTOT*128)
  float* sc   = mt;  // score2 overlays mt (written only after last mt read)
  float* wqt  = ws + 13279232;                        //    16,384 f
  float* mct  = ws + 13295616;                        //    16,384 f

  hipLaunchKernelGGL(k_wt, dim3(128), dim3(256), 0, stream, Wq, MC, wqt, mct);
  hipLaunchKernelGGL(k_qcalc, dim3(400), dim3(256), 0, stream, x, wqt, qf, q_ws);
  hipLaunchKernelGGL(k_mask_t, dim3(19, 2, BB), dim3(256), 0, stream, mask, mt);
  hipLaunchKernelGGL(k_mha, dim3(1024), dim3(512), 0, stream, kk, vv, q_ws, mt, part);
  hipLaunchKernelGGL(k_combine, dim3(400), dim3(256), 0, stream, part, mct, mh);
  hipLaunchKernelGGL(k_score2, dim3(1024), dim3(256), 0, stream, mh, shk, sc);
  hipLaunchKernelGGL(k_finsm, dim3(6400), dim3(256), 0, stream, sc, eb, cn, mask, out);
}